// Round 14
// baseline (157.785 us; speedup 1.0000x reference)
//
#include <hip/hip_runtime.h>
#include <hip/hip_bf16.h>
#include <math.h>

// Shapes: B=1, M=2, L=256, D=256, D2=512, S=128.
// Row convention: r = t*512 + (m*256 + l), t in {0(x),1(mouth)}.

#define D_   256
#define D2_  512
#define S_   128

typedef short  bf16x8 __attribute__((ext_vector_type(8)));
typedef short  bf16x4 __attribute__((ext_vector_type(4)));
typedef float  f32x4  __attribute__((ext_vector_type(4)));

__device__ __forceinline__ float silu_f(float v) {
    return v / (1.f + __expf(-v));
}
__device__ __forceinline__ float softplus_f(float v) {
    return fmaxf(v, 0.f) + log1pf(__expf(-fabsf(v)));
}
__device__ __forceinline__ short f2bf(float f) {
    __hip_bfloat16 h = __float2bfloat16(f);
    return reinterpret_cast<short&>(h);
}

// ---- D1: MFMA dual-output GEMM (verbatim from R12; proven 136us/absmax 7.8e-3) ----
// tile 32(M) x 64(N), 256 threads (4 waves), KC=32.
template<bool NORM, int ACT1, int ACT2>
__global__ __launch_bounds__(256) void gemm_mfma_k(
        const float* __restrict__ A0, const float* __restrict__ A1,
        const float* __restrict__ nw,
        const float* __restrict__ W1, const float* __restrict__ bias1,
        float* __restrict__ O1, int nct1, int ldo1, int n1,
        const float* __restrict__ W2, const float* __restrict__ bias2,
        float* __restrict__ O2, int nct2, int ldo2, int K) {
    __shared__ __align__(16) short a_lds[2][32 * 56];
    __shared__ __align__(16) short w_lds[2][64 * 56];
    const int b = blockIdx.x;
    const float *W, *bias; float* O; int ldo, act, rt, ct;
    if (b < n1) { W = W1; bias = bias1; O = O1; ldo = ldo1; act = ACT1; rt = b / nct1; ct = b % nct1; }
    else { int bb = b - n1; W = W2; bias = bias2; O = O2; ldo = ldo2; act = ACT2; rt = bb / nct2; ct = bb % nct2; }
    const int r0 = rt * 32, c0 = ct * 64;
    const int t = threadIdx.x;
    const int sr = t >> 3, sk = (t & 7) << 2;     // A: 8 thr/row, 4 floats each
    const int wc = t >> 2, wk = (t & 3) << 3;     // W: 4 thr/col, 8 floats each
    const int rowA = r0 + sr;
    const float* rowbase = (rowA < 512) ? (A0 + (size_t)rowA * K)
                                        : (A1 + (size_t)(rowA - 512) * K);
    float ascale = 1.f;
    if (NORM) {
        float ssum = 0.f;
        const float* rp = rowbase + (t & 7) * 32;
#pragma unroll
        for (int q = 0; q < 8; ++q) {
            float4 v = *(const float4*)(rp + q * 4);
            ssum += v.x * v.x + v.y * v.y + v.z * v.z + v.w * v.w;
        }
        ssum += __shfl_xor(ssum, 1);
        ssum += __shfl_xor(ssum, 2);
        ssum += __shfl_xor(ssum, 4);
        ascale = 1.f / sqrtf(ssum + 1e-5f);
    }
    const float* Ag = rowbase + sk;
    const float* Wg = W + (size_t)(c0 + wc) * K + wk;
    float4 areg  = *(const float4*)Ag;
    float4 wrega = *(const float4*)Wg;
    float4 wregb = *(const float4*)(Wg + 4);
    float4 nwreg = NORM ? *(const float4*)(nw + sk) : make_float4(0.f, 0.f, 0.f, 0.f);
    const int wv = t >> 6, lane = t & 63;
    const int aoff  = ((wv & 1) * 16 + (lane & 15)) * 56 + (lane >> 4) * 8;
    const int boff0 = ((wv >> 1) * 32 + (lane & 15)) * 56 + (lane >> 4) * 8;
    const int boff1 = boff0 + 16 * 56;
    f32x4 acc0 = {0.f, 0.f, 0.f, 0.f};
    f32x4 acc1 = {0.f, 0.f, 0.f, 0.f};
    const int nch = K >> 5;
    for (int ch = 0; ch < nch; ++ch) {
        const int p = ch & 1;
        float4 a = areg;
        if (NORM) {
            a.x *= ascale * nwreg.x; a.y *= ascale * nwreg.y;
            a.z *= ascale * nwreg.z; a.w *= ascale * nwreg.w;
        }
        bf16x4 av; av[0] = f2bf(a.x); av[1] = f2bf(a.y); av[2] = f2bf(a.z); av[3] = f2bf(a.w);
        *(bf16x4*)&a_lds[p][sr * 56 + sk] = av;
        bf16x8 wv8;
        wv8[0] = f2bf(wrega.x); wv8[1] = f2bf(wrega.y); wv8[2] = f2bf(wrega.z); wv8[3] = f2bf(wrega.w);
        wv8[4] = f2bf(wregb.x); wv8[5] = f2bf(wregb.y); wv8[6] = f2bf(wregb.z); wv8[7] = f2bf(wregb.w);
        *(bf16x8*)&w_lds[p][wc * 56 + wk] = wv8;
        __syncthreads();
        if (ch + 1 < nch) {
            const int ko = (ch + 1) << 5;
            areg  = *(const float4*)(Ag + ko);
            wrega = *(const float4*)(Wg + ko);
            wregb = *(const float4*)(Wg + ko + 4);
            if (NORM) nwreg = *(const float4*)(nw + ko + sk);
        }
        bf16x8 af  = *(const bf16x8*)&a_lds[p][aoff];
        bf16x8 bf0 = *(const bf16x8*)&w_lds[p][boff0];
        bf16x8 bf1 = *(const bf16x8*)&w_lds[p][boff1];
        acc0 = __builtin_amdgcn_mfma_f32_16x16x32_bf16(af, bf0, acc0, 0, 0, 0);
        acc1 = __builtin_amdgcn_mfma_f32_16x16x32_bf16(af, bf1, acc1, 0, 0, 0);
    }
    const int rowE = r0 + (wv & 1) * 16 + (lane >> 4) * 4;
    const int colE = c0 + (wv >> 1) * 32 + (lane & 15);
#pragma unroll
    for (int cb = 0; cb < 2; ++cb) {
        const f32x4 acc = cb ? acc1 : acc0;
        const int col = colE + cb * 16;
        const float bv = bias[col];
#pragma unroll
        for (int i = 0; i < 4; ++i) {
            float v = acc[i] + bv;
            if (act == 1)      v = silu_f(v);
            else if (act == 2) v = softplus_f(v);
            O[(size_t)(rowE + i) * ldo + col] = v;
        }
    }
}

// ---- D2: conv + fc1 + fc2 + ssm + combine + out, one block per (m, l-pair) ----
// 256 blocks x 512 threads. Weight matvecs use the R12-proven 16-lane-coalesced
// pattern (16 lanes x 16B = 256B contiguous per weight row), with all 4 (t,lr)
// rows sharing each weight read. No xc/delta/Bm global round-trips.
__global__ __launch_bounds__(512) void mega2_k(
        const float* __restrict__ xp,   const float* __restrict__ res,
        const float* __restrict__ convW, const float* __restrict__ convB,
        const float* __restrict__ fc1W, const float* __restrict__ fc1b,
        const float* __restrict__ fc2W, const float* __restrict__ fc2b,
        const float* __restrict__ A,    const float* __restrict__ outW,
        const float* __restrict__ outb, float* __restrict__ out) {
    __shared__ float xph[2][2][4][512];   // xp halo [t][i][h][w], h -> l0-1+h (16KB)
    __shared__ float xcs[2][2][512];      // conv+silu [t][lr][w]                (8KB)
    __shared__ float deltas[2][2][512];   // softplus(fc1) [t][lr][d]            (8KB)
    __shared__ float Bms[2][2][S_];       // fc2 [t][lr][n]                      (2KB)
    __shared__ float combs[2][D2_];       // combined [lr][d]                    (4KB)
    __shared__ float red[8];
    const int tid = threadIdx.x;
    const int m  = blockIdx.x >> 7;             // 0..1
    const int l0 = (blockIdx.x & 127) << 1;     // 0,2,..,254

    // ---- A: load xp halo rows l0-1..l0+2, t=0,1, i=0,1 (zeros outside) [R8-proven] ----
#pragma unroll
    for (int jj = 0; jj < 4; ++jj) {
        int f   = tid + jj * 512;               // 0..2047 float4 slots
        int w4  = f & 127;
        int row = f >> 7;                       // 0..15
        int tt = row >> 3, ii = (row >> 2) & 1, h = row & 3;
        int l = l0 - 1 + h;
        float4 v = make_float4(0.f, 0.f, 0.f, 0.f);
        if (l >= 0 && l <= 255)
            v = *(const float4*)(xp + (size_t)(tt * 512 + ii * 256 + l) * 512 + w4 * 4);
        *(float4*)&xph[tt][ii][h][w4 * 4] = v;
    }
    __syncthreads();                                            // bar1: xph ready
    // ---- B: conv3x3 + bias + silu -> xcs [R8-proven] ----
    {
        const int w = tid;                      // 0..511
        float cw[2][3][3];
#pragma unroll
        for (int ii = 0; ii < 2; ++ii)
#pragma unroll
            for (int dh = 0; dh < 3; ++dh)
#pragma unroll
                for (int dw = 0; dw < 3; ++dw)
                    cw[ii][dh][dw] = convW[((m * 2 + ii) * 3 + dh) * 3 + dw];
        const float cb = convB[m];
#pragma unroll
        for (int tt = 0; tt < 2; ++tt)
#pragma unroll
            for (int lr = 0; lr < 2; ++lr) {
                float acc = cb;
#pragma unroll
                for (int ii = 0; ii < 2; ++ii)
#pragma unroll
                    for (int dh = 0; dh < 3; ++dh) {
                        const float* src = &xph[tt][ii][lr + dh][0];
                        if (w >= 1)   acc += src[w - 1] * cw[ii][dh][0];
                                      acc += src[w    ] * cw[ii][dh][1];
                        if (w <= 510) acc += src[w + 1] * cw[ii][dh][2];
                    }
                xcs[tt][lr][w] = silu_f(acc);
            }
    }
    __syncthreads();                                            // bar2: xcs ready
    // ---- C: fc1 -> softplus -> deltas; 16-lane groups, 4 rows share W reads ----
    {
        const int g = tid >> 4;                 // 0..31
        const int j = tid & 15;
#pragma unroll 2
        for (int rnd = 0; rnd < 16; ++rnd) {
            const int c = rnd * 32 + g;
            const float4* wrow = (const float4*)(fc1W + (size_t)c * 512);
            float a00 = 0.f, a01 = 0.f, a10 = 0.f, a11 = 0.f;
#pragma unroll
            for (int it = 0; it < 8; ++it) {
                const int k = it * 64 + j * 4;
                float4 w4 = wrow[it * 16 + j];
                a00 += w4.x * xcs[0][0][k] + w4.y * xcs[0][0][k + 1]
                     + w4.z * xcs[0][0][k + 2] + w4.w * xcs[0][0][k + 3];
                a01 += w4.x * xcs[0][1][k] + w4.y * xcs[0][1][k + 1]
                     + w4.z * xcs[0][1][k + 2] + w4.w * xcs[0][1][k + 3];
                a10 += w4.x * xcs[1][0][k] + w4.y * xcs[1][0][k + 1]
                     + w4.z * xcs[1][0][k + 2] + w4.w * xcs[1][0][k + 3];
                a11 += w4.x * xcs[1][1][k] + w4.y * xcs[1][1][k + 1]
                     + w4.z * xcs[1][1][k + 2] + w4.w * xcs[1][1][k + 3];
            }
#pragma unroll
            for (int off = 1; off < 16; off <<= 1) {
                a00 += __shfl_xor(a00, off);
                a01 += __shfl_xor(a01, off);
                a10 += __shfl_xor(a10, off);
                a11 += __shfl_xor(a11, off);
            }
            if (j == 0) {
                const float b = fc1b[c];
                deltas[0][0][c] = softplus_f(a00 + b);
                deltas[0][1][c] = softplus_f(a01 + b);
                deltas[1][0][c] = softplus_f(a10 + b);
                deltas[1][1][c] = softplus_f(a11 + b);
            }
        }
        // ---- D: fc2 -> Bms (same pattern, 4 rounds) ----
#pragma unroll
        for (int rnd = 0; rnd < 4; ++rnd) {
            const int c = rnd * 32 + g;
            const float4* wrow = (const float4*)(fc2W + (size_t)c * 512);
            float a00 = 0.f, a01 = 0.f, a10 = 0.f, a11 = 0.f;
#pragma unroll
            for (int it = 0; it < 8; ++it) {
                const int k = it * 64 + j * 4;
                float4 w4 = wrow[it * 16 + j];
                a00 += w4.x * xcs[0][0][k] + w4.y * xcs[0][0][k + 1]
                     + w4.z * xcs[0][0][k + 2] + w4.w * xcs[0][0][k + 3];
                a01 += w4.x * xcs[0][1][k] + w4.y * xcs[0][1][k + 1]
                     + w4.z * xcs[0][1][k + 2] + w4.w * xcs[0][1][k + 3];
                a10 += w4.x * xcs[1][0][k] + w4.y * xcs[1][0][k + 1]
                     + w4.z * xcs[1][0][k + 2] + w4.w * xcs[1][0][k + 3];
                a11 += w4.x * xcs[1][1][k] + w4.y * xcs[1][1][k + 1]
                     + w4.z * xcs[1][1][k + 2] + w4.w * xcs[1][1][k + 3];
            }
#pragma unroll
            for (int off = 1; off < 16; off <<= 1) {
                a00 += __shfl_xor(a00, off);
                a01 += __shfl_xor(a01, off);
                a10 += __shfl_xor(a10, off);
                a11 += __shfl_xor(a11, off);
            }
            if (j == 0) {
                const float b = fc2b[c];
                Bms[0][0][c] = a00 + b;
                Bms[0][1][c] = a01 + b;
                Bms[1][0][c] = a10 + b;
                Bms[1][1][c] = a11 + b;
            }
        }
    }
    __syncthreads();                                            // bar3: deltas, Bms
    // ---- E: per-(t,lr) sum(Bm^2) -> red [R12-proven] ----
    {
        const int g4 = tid >> 7;                // 0..3: t=g4>>1, lr=g4&1
        const int tt = g4 >> 1, lr = g4 & 1, n = tid & 127;
        float bv = Bms[tt][lr][n];
        float sq = bv * bv;
        for (int off = 32; off; off >>= 1) sq += __shfl_xor(sq, off);
        if ((tid & 63) == 0) red[tid >> 6] = sq;   // s2(t,lr)=red[2g]+red[2g+1]
    }
    __syncthreads();                                            // bar4: red ready
    // ---- F: ssm + silu + combine [R12-proven, LDS-sourced] ----
    {
        const int d = tid;
        float s2[2][2];
#pragma unroll
        for (int g4 = 0; g4 < 4; ++g4) s2[g4 >> 1][g4 & 1] = red[2 * g4] + red[2 * g4 + 1];
        float dl[2][2], xcv[2][2], rsv[2];
#pragma unroll
        for (int tt = 0; tt < 2; ++tt)
#pragma unroll
            for (int lr = 0; lr < 2; ++lr) {
                dl[tt][lr]  = deltas[tt][lr][d];
                xcv[tt][lr] = xcs[tt][lr][d];
            }
        rsv[0] = res[(size_t)(m * 256 + l0) * D2_ + d];
        rsv[1] = res[(size_t)(m * 256 + l0 + 1) * D2_ + d];
        float accs[2][2] = {};
        const float4* arow = (const float4*)(A + (size_t)d * S_);
        for (int k4 = 0; k4 < 32; ++k4) {
            float4 a4 = arow[k4];
            const int n = k4 * 4;
#pragma unroll
            for (int cmp = 0; cmp < 4; ++cmp) {
                float a = (cmp == 0) ? a4.x : (cmp == 1) ? a4.y : (cmp == 2) ? a4.z : a4.w;
#pragma unroll
                for (int tt = 0; tt < 2; ++tt)
#pragma unroll
                    for (int lr = 0; lr < 2; ++lr)
                        accs[tt][lr] += Bms[tt][lr][n + cmp] * __expf(dl[tt][lr] * a);
            }
        }
#pragma unroll
        for (int lr = 0; lr < 2; ++lr) {
            float sx = accs[0][lr] + xcv[0][lr] * dl[0][lr] * s2[0][lr];
            float sm = accs[1][lr] + xcv[1][lr] * dl[1][lr] * s2[1][lr];
            combs[lr][d] = (silu_f(sx) + silu_f(sm)) * rsv[lr];
        }
    }
    __syncthreads();                                            // bar5: combs ready
    // ---- G: out = comb @ outW^T + outb [R12-proven] ----
    {
        const int wv = tid >> 6, lane = tid & 63;
        const int j = lane & 15, cg = lane >> 4;
#pragma unroll
        for (int rnd = 0; rnd < 8; ++rnd) {
            const int c = wv * 32 + rnd * 4 + cg;
            const float4* wrow = (const float4*)(outW + (size_t)c * D2_);
            float a0 = 0.f, a1 = 0.f;
#pragma unroll
            for (int it = 0; it < 8; ++it) {
                const int k = it * 64 + j * 4;
                float4 w4 = wrow[it * 16 + j];
                a0 += w4.x * combs[0][k] + w4.y * combs[0][k + 1]
                    + w4.z * combs[0][k + 2] + w4.w * combs[0][k + 3];
                a1 += w4.x * combs[1][k] + w4.y * combs[1][k + 1]
                    + w4.z * combs[1][k + 2] + w4.w * combs[1][k + 3];
            }
            a0 += __shfl_xor(a0, 1); a0 += __shfl_xor(a0, 2);
            a0 += __shfl_xor(a0, 4); a0 += __shfl_xor(a0, 8);
            a1 += __shfl_xor(a1, 1); a1 += __shfl_xor(a1, 2);
            a1 += __shfl_xor(a1, 4); a1 += __shfl_xor(a1, 8);
            if (j == 0) {
                const float b = outb[c];
                out[(size_t)(m * 256 + l0)     * D_ + c] = a0 + b;
                out[(size_t)(m * 256 + l0 + 1) * D_ + c] = a1 + b;
            }
        }
    }
}

extern "C" void kernel_launch(void* const* d_in, const int* in_sizes, int n_in,
                              void* d_out, int out_size, void* d_ws, size_t ws_size,
                              hipStream_t stream) {
    const float* x      = (const float*)d_in[0];
    const float* mouth  = (const float*)d_in[1];
    const float* norm_w = (const float*)d_in[2];
    const float* inp_W  = (const float*)d_in[3];
    const float* inp_b  = (const float*)d_in[4];
    const float* out_W  = (const float*)d_in[5];
    const float* out_b  = (const float*)d_in[6];
    const float* Dlin_W = (const float*)d_in[7];
    const float* Dlin_b = (const float*)d_in[8];
    const float* conv_W = (const float*)d_in[9];
    const float* conv_b = (const float*)d_in[10];
    const float* fc1_W  = (const float*)d_in[11];
    const float* fc1_b  = (const float*)d_in[12];
    const float* fc2_W  = (const float*)d_in[13];
    const float* fc2_b  = (const float*)d_in[14];
    const float* A      = (const float*)d_in[15];

    float* ws  = (float*)d_ws;
    float* xp  = ws;                        // 1024*512
    float* res = xp + 1024 * 512;           // 512*512
    float* out = (float*)d_out;

    // D1: in-block rmsnorm + dual MFMA GEMM:
    //   xp  = xn @ inp_W^T + inp_b      (1024x512 -> 256 jobs)
    //   res = silu(xn_x @ Dlin_W^T + b) (512x512  -> 128 jobs); total 384.
    gemm_mfma_k<true, 0, 1><<<384, 256, 0, stream>>>(
        x, mouth, norm_w,
        inp_W, inp_b, xp, 8, 512, 256,
        Dlin_W, Dlin_b, res, 8, 512, 256);
    // D2: conv -> fc1/fc2 -> ssm -> combine -> out, row-local per (m, l-pair)
    mega2_k<<<256, 512, 0, stream>>>(xp, res, conv_W, conv_b,
                                     fc1_W, fc1_b, fc2_W, fc2_b,
                                     A, out_W, out_b, out);
}